// Round 6
// baseline (122.357 us; speedup 1.0000x reference)
//
#include <hip/hip_runtime.h>
#include <math.h>

#define NCOLS 5000
#define NF4   1250            // NCOLS / 4
#define NF4P  1280            // padded: chunk-4 DMA writes up to index 1279
#define BLOCK 256
#define NWAVES 4
#define NITER 5               // ceil(NF4 / BLOCK)
#define TOPKK 10
#define TR    3               // threshold rounds per wave (4*3 >= 12 >= k)
#define CAP   128             // candidate capacity per path (expect ~40)

// Monotone-ascending mapping float -> uint32 (total order on finite floats).
__device__ __forceinline__ unsigned mono_f32(float f) {
  unsigned u = __float_as_uint(f);
  return (u & 0x80000000u) ? ~u : (u | 0x80000000u);
}

__device__ __forceinline__ float wave_sum_f(float v) {
#pragma unroll
  for (int o = 1; o < 64; o <<= 1) v += __shfl_xor(v, o);
  return v;
}
__device__ __forceinline__ int wave_sum_i(int v) {
#pragma unroll
  for (int o = 1; o < 64; o <<= 1) v += __shfl_xor(v, o);
  return v;
}
__device__ __forceinline__ unsigned wave_max_u(unsigned v) {
#pragma unroll
  for (int o = 1; o < 64; o <<= 1) {
    unsigned w = __shfl_xor(v, o);
    v = w > v ? w : v;
  }
  return v;
}

// Async global->LDS DMA, 16 B per lane. Dest must be wave-uniform base
// (HW writes base + lane*16); source is per-lane. No VGPR payload -> the
// compiler cannot sink/serialize these (R0/R5 showed it does for reg loads).
__device__ __forceinline__ void gl_lds16(const float4* g, float4* l) {
  __builtin_amdgcn_global_load_lds(
      (const __attribute__((address_space(1))) void*)(g),
      (__attribute__((address_space(3))) void*)(l), 16, 0, 0);
}

extern "C" __global__ __launch_bounds__(BLOCK, 2)
void row_loss_kernel(const float* __restrict__ up, const float* __restrict__ down,
                     const float* __restrict__ yt, const int* __restrict__ masks,
                     float* __restrict__ ws) {
  __shared__ float4 y_s[NF4P];         // 20480 B, stays resident (keys + KL)
  __shared__ float4 u_s[NF4P];         // 20480 B (sums + top-k gather)
  __shared__ float4 d_s[NF4P];         // 20480 B
  __shared__ float red_f[6][NWAVES];   // sq, sp, seyy, seyu, aspu, aspd
  __shared__ int red_i[NWAVES];        // nv partials
  __shared__ unsigned t1w_t[NWAVES];   // per-wave TR-th-largest thread-max (top)
  __shared__ unsigned t1w_b[NWAVES];   // same, bottom (~key space)
  __shared__ unsigned keys_t[CAP]; __shared__ int col_t[CAP];
  __shared__ unsigned keys_b[CAP]; __shared__ int col_b[CAP];
  __shared__ int ct, cb;
  __shared__ float s_res[2];           // SU, SD

  const int tid = threadIdx.x;
  const int lane = tid & 63;
  const int wv = tid >> 6;
  const int row = blockIdx.x;
  const long long b4 = (long long)row * NF4;

  if (tid == 0) { ct = 0; cb = 0; }

  const float4* up4 = (const float4*)up + b4;
  const float4* dn4 = (const float4*)down + b4;
  const float4* yt4 = (const float4*)yt + b4;
  const int4*   mk4 = (const int4*)masks + b4;

  // ---- masks to registers (5 int4 = 20 VGPRs; cap is 256, no pressure).
  int4 m4[NITER];
#pragma unroll
  for (int j = 0; j < NITER; ++j) {
    const int f = j * BLOCK + tid;
    const int fc = f < NF4 ? f : NF4 - 1;
    m4[j] = mk4[fc];
  }

  // ---- Fire-and-forget DMA: 15 gl_lds per wave, all issued upfront.
  // Issue order (per wave): y0..y4, then (u0,d0)..(u4,d4). gl_lds ops all
  // write LDS -> compiler preserves their relative order; the mask reg-loads
  // may float, which only makes the counted waits below stricter (safe).
  {
    const int wb = wv * 64;
#pragma unroll
    for (int j = 0; j < NITER; ++j) {
      const int f = j * BLOCK + wb + lane;
      const int fc = f < NF4 ? f : NF4 - 1;
      gl_lds16(yt4 + fc, y_s + j * BLOCK + wb);
    }
#pragma unroll
    for (int j = 0; j < NITER; ++j) {
      const int f = j * BLOCK + wb + lane;
      const int fc = f < NF4 ? f : NF4 - 1;
      gl_lds16(up4 + fc, u_s + j * BLOCK + wb);
      gl_lds16(dn4 + fc, d_s + j * BLOCK + wb);
    }
  }
  __builtin_amdgcn_sched_barrier(0);

  // ---- Streaming consume: chunk j ready when outstanding <= 2*(4-j).
  int vmask = 0;                       // bit j*4+c = element valid
  float sq = 0.f, sp = 0.f, seyy = 0.f, seyu = 0.f, aspu = 0.f, aspd = 0.f;
  unsigned tmax = 0u, tbmax = 0u;

#define ELEM(bit, Y, U, D, M, INB)                                      \
  {                                                                     \
    const bool valid = (INB) && ((M) > 0);                              \
    const float y = (Y), u = (U), d = (D);                              \
    const unsigned kd = valid ? mono_f32(y) : 0u;                       \
    const unsigned kb = valid ? ~kd : 0u;                               \
    vmask |= valid ? (1 << (bit)) : 0;                                  \
    tmax = kd > tmax ? kd : tmax;                                       \
    tbmax = kb > tbmax ? kb : tbmax;                                    \
    if (valid) {                                                        \
      const float ey = __expf(y);                                       \
      const float eu = __expf(u);                                       \
      const float ed = __expf(d);                                       \
      sq += ey; seyy += ey * y; seyu += ey * u; sp += eu;               \
      aspu += (u > 15.f) ? u : __logf(1.f + eu);                        \
      aspd += (d > 15.f) ? d : __logf(1.f + ed);                        \
    }                                                                   \
  }

#define CHUNK(J, VM, INB)                                               \
  {                                                                     \
    asm volatile("s_waitcnt vmcnt(" VM ")" ::: "memory");               \
    __builtin_amdgcn_sched_barrier(0);                                  \
    const float4 yv = y_s[(J) * BLOCK + tid];                           \
    const float4 uv = u_s[(J) * BLOCK + tid];                           \
    const float4 dv = d_s[(J) * BLOCK + tid];                           \
    const int4 mm = m4[(J)];                                            \
    ELEM((J) * 4 + 0, yv.x, uv.x, dv.x, mm.x, INB)                      \
    ELEM((J) * 4 + 1, yv.y, uv.y, dv.y, mm.y, INB)                      \
    ELEM((J) * 4 + 2, yv.z, uv.z, dv.z, mm.z, INB)                      \
    ELEM((J) * 4 + 3, yv.w, uv.w, dv.w, mm.w, INB)                      \
  }

  const bool inb2 = tid < (NF4 - 4 * BLOCK);   // 226
  CHUNK(0, "8", true)
  CHUNK(1, "6", true)
  CHUNK(2, "4", true)
  CHUNK(3, "2", true)
  CHUNK(4, "0", inb2)   // vmcnt(0): drains this wave's DMA before any barrier
#undef CHUNK
#undef ELEM

  // ---- Wave reduces of scalars.
  int nv_l = wave_sum_i(__popc((unsigned)vmask));
  sq = wave_sum_f(sq);
  sp = wave_sum_f(sp);
  seyy = wave_sum_f(seyy);
  seyu = wave_sum_f(seyu);
  aspu = wave_sum_f(aspu);
  aspd = wave_sum_f(aspd);
  if (lane == 0) {
    red_i[wv] = nv_l;
    red_f[0][wv] = sq;  red_f[1][wv] = sp;
    red_f[2][wv] = seyy; red_f[3][wv] = seyu;
    red_f[4][wv] = aspu; red_f[5][wv] = aspd;
  }

  // ---- Per-wave filter threshold, TR=3 rounds (top/bottom interleaved).
  // min over waves of (TR-th largest thread-max) guarantees >= 4*3 = 12
  // >= TOPKK candidates above threshold.
  {
    unsigned vt = tmax, vb = tbmax, t1t = 0u, t1b_ = 0u;
#pragma unroll
    for (int r = 0; r < TR; ++r) {
      unsigned mt = wave_max_u(vt);
      unsigned mb = wave_max_u(vb);
      if (vt == mt) vt = 0u;
      if (vb == mb) vb = 0u;
      t1t = mt; t1b_ = mb;
    }
    if (lane == 0) { t1w_t[wv] = t1t; t1w_b[wv] = t1b_; }
  }
  __syncthreads();

  int nv = 0;
#pragma unroll
  for (int w = 0; w < NWAVES; ++w) nv += red_i[w];
  const int k = nv < TOPKK ? nv : TOPKK;

  unsigned t1 = 0xFFFFFFFFu, t1b = 0xFFFFFFFFu;
#pragma unroll
  for (int w = 0; w < NWAVES; ++w) {
    t1 = t1w_t[w] < t1 ? t1w_t[w] : t1;
    t1b = t1w_b[w] < t1b ? t1w_b[w] : t1b;
  }

  // ---- Compaction: recompute keys from LDS-resident y (no km array).
#pragma unroll
  for (int j = 0; j < NITER; ++j) {
    const int mbits = (vmask >> (j * 4)) & 0xF;
    if (mbits) {
      const float4 yv = y_s[j * BLOCK + tid];
      const float ya[4] = {yv.x, yv.y, yv.z, yv.w};
#pragma unroll
      for (int c = 0; c < 4; ++c) {
        if (mbits & (1 << c)) {
          const unsigned kd = mono_f32(ya[c]);
          const int col = ((j * BLOCK + tid) << 2) + c;
          if (kd >= t1) {
            int i = atomicAdd(&ct, 1);
            if (i < CAP) { keys_t[i] = kd; col_t[i] = col; }
          }
          const unsigned kb = ~kd;
          if (kb >= t1b) {
            int i = atomicAdd(&cb, 1);
            if (i < CAP) { keys_b[i] = kb; col_b[i] = col; }
          }
        }
      }
    }
  }
  __syncthreads();

  // ---- Waves 0/1: exact k-th key via 32-step ballot binary search, then
  //      gather selected u/d straight from LDS.
  if (wv == 0) {
    const int n = ct < CAP ? ct : CAP;
    const unsigned k0 = (lane < n) ? keys_t[lane] : 0u;
    const unsigned k1 = (64 + lane < n) ? keys_t[64 + lane] : 0u;
    unsigned thr = 0u;
#pragma unroll
    for (int b = 31; b >= 0; --b) {
      const unsigned t = thr | (1u << b);
      const int c = __popcll(__ballot(k0 >= t)) + __popcll(__ballot(k1 >= t));
      thr = (c >= k) ? t : thr;
    }
    float su = 0.f;
    if (k0 >= thr && k0 != 0u) su += ((const float*)u_s)[col_t[lane]];
    if (k1 >= thr && k1 != 0u) su += ((const float*)u_s)[col_t[64 + lane]];
    su = wave_sum_f(su);
    if (lane == 0) s_res[0] = su;
  } else if (wv == 1) {
    const int n = cb < CAP ? cb : CAP;
    const unsigned k0 = (lane < n) ? keys_b[lane] : 0u;
    const unsigned k1 = (64 + lane < n) ? keys_b[64 + lane] : 0u;
    unsigned thr = 0u;
#pragma unroll
    for (int b = 31; b >= 0; --b) {
      const unsigned t = thr | (1u << b);
      const int c = __popcll(__ballot(k0 >= t)) + __popcll(__ballot(k1 >= t));
      thr = (c >= k) ? t : thr;
    }
    float sd = 0.f;
    if (k0 >= thr && k0 != 0u) sd += ((const float*)d_s)[col_b[lane]];
    if (k1 >= thr && k1 != 0u) sd += ((const float*)d_s)[col_b[64 + lane]];
    sd = wave_sum_f(sd);
    if (lane == 0) s_res[1] = sd;
  }
  __syncthreads();

  if (tid == 0) {
    float loss = 0.f;
    if (nv > 0) {
      float SQ = 0.f, SP = 0.f, SYY = 0.f, SYU = 0.f, ASU = 0.f, ASD = 0.f;
#pragma unroll
      for (int w = 0; w < NWAVES; ++w) {
        SQ += red_f[0][w]; SP += red_f[1][w];
        SYY += red_f[2][w]; SYU += red_f[3][w];
        ASU += red_f[4][w]; ASD += red_f[5][w];
      }
      const float SU = s_res[0];
      const float SD = s_res[1];
      // KL closed form: sum q*(logq-logp) = (Seyy-Seyu)/Sq - log(Sq) + log(Sp)
      const float kl = (SYY - SYU) / SQ - __logf(SQ) + __logf(SP);
      const float up_loss = ASU - SU;  // sum softplus(u) - sum_{topk} u
      const float dn_loss = ASD - SD;  // sum softplus(d) - sum_{botk} d
      loss = (up_loss + 0.5f * dn_loss + 0.3f * kl) / (float)nv;
    }
    ws[row] = loss;                    // plain store; reducer sums
  }
}

// Deterministic 1-block tree reduction of the per-row losses.
extern "C" __global__ __launch_bounds__(256)
void reduce_loss_kernel(const float* __restrict__ ws, float* __restrict__ out,
                        int n, float inv_n) {
  __shared__ float part[4];
  const int tid = threadIdx.x;
  const int lane = tid & 63;
  const int wv = tid >> 6;
  float s = 0.f;
  const int n4 = n >> 2;
  const float4* w4 = (const float4*)ws;
  for (int i = tid; i < n4; i += 256) {
    const float4 v = w4[i];
    s += (v.x + v.y) + (v.z + v.w);
  }
  for (int i = (n4 << 2) + tid; i < n; i += 256) s += ws[i];
  s = wave_sum_f(s);
  if (lane == 0) part[wv] = s;
  __syncthreads();
  if (tid == 0) out[0] = (part[0] + part[1] + part[2] + part[3]) * inv_n;
}

extern "C" void kernel_launch(void* const* d_in, const int* in_sizes, int n_in,
                              void* d_out, int out_size, void* d_ws, size_t ws_size,
                              hipStream_t stream) {
  const float* up_logits   = (const float*)d_in[0];
  const float* down_logits = (const float*)d_in[1];
  const float* y_true      = (const float*)d_in[2];
  const int*   masks       = (const int*)d_in[3];

  const int nrows = in_sizes[0] / NCOLS;

  row_loss_kernel<<<nrows, BLOCK, 0, stream>>>(up_logits, down_logits, y_true,
                                               masks, (float*)d_ws);
  reduce_loss_kernel<<<1, 256, 0, stream>>>((const float*)d_ws, (float*)d_out,
                                            nrows, 1.0f / (float)nrows);
}